// Round 3
// baseline (211.406 us; speedup 1.0000x reference)
//
#include <hip/hip_runtime.h>
#include <math.h>

// Problem dims (fixed by the reference)
#define B_DIM   128
#define C_DIM   512
#define HW      784      // 28*28
#define HW4     196      // HW/4 float4s per (b,c) row
#define NCLS    1000
#define MBINS   50
#define NROWS   (B_DIM * C_DIM)   // 65536
#define ALPHA   100.0f
#define OUT_ELTS (C_DIM * MBINS)  // 25600 floats
#define PH_BLOCKS 2048            // pool/hist grid (grid-stride, 4 waves/block)

__device__ __forceinline__ float wave_reduce_sum(float v) {
    #pragma unroll
    for (int off = 32; off > 0; off >>= 1) v += __shfl_xor(v, off, 64);
    return v;
}

// ---------------- Kernel 1: spatial sum pool + d_out zeroing ---------------
// Grid-stride: 2048 blocks x 4 waves = 8192 waves, 8 rows each. Per-row
// arithmetic identical to previous rounds (one wave per row, same load/reduce
// order) -- only the row->wave mapping changed, which rows don't observe.
__global__ void pool_kernel(const float* __restrict__ act,
                            float* __restrict__ pooled,
                            float* __restrict__ hist_out) {
    if (blockIdx.x < OUT_ELTS / 256) {
        hist_out[blockIdx.x * 256 + threadIdx.x] = 0.0f;
    }
    int wid  = threadIdx.x >> 6;
    int lane = threadIdx.x & 63;
    int wgid = blockIdx.x * 4 + wid;
    for (int row = wgid; row < NROWS; row += PH_BLOCKS * 4) {
        const float4* p = reinterpret_cast<const float4*>(act) + (size_t)row * HW4;
        float s = 0.f;
        #pragma unroll
        for (int i = 0; i < 3; ++i) {
            float4 v = p[lane + i * 64];
            s += (v.x + v.y) + (v.z + v.w);
        }
        if (lane < 4) {
            float4 v = p[192 + lane];
            s += (v.x + v.y) + (v.z + v.w);
        }
        s = wave_reduce_sum(s);
        if (lane == 0) pooled[row] = s;
    }
}

// ---------------- Kernel 2: fused logits + softmax + gA --------------------
// One block per b (128 blocks x 512 threads). Value-producing arithmetic is
// bitwise-identical to the previous 2-kernel path:
//  - each logit n: same serial c-loop 0..511;
//  - softmax: EXACT previous 256-thread pattern (threads >=256 idle there);
//  - each gA[c]: same float4 dot over n.
__global__ void smax_gcalc_kernel(const float* __restrict__ pooled,
                                  const float* __restrict__ W,
                                  float* __restrict__ gA) {
    __shared__ float sp[C_DIM];
    __shared__ float slog[NCLS];
    __shared__ float red[4];
    int b   = blockIdx.x;
    int tid = threadIdx.x;

    for (int c = tid; c < C_DIM; c += 512) sp[c] = pooled[b * C_DIM + c];
    __syncthreads();

    // logits -> LDS (each n self-contained; thread layout irrelevant)
    for (int n = tid; n < NCLS; n += 512) {
        float acc = 0.f;
        #pragma unroll 4
        for (int c = 0; c < C_DIM; ++c) acc += sp[c] * W[c * NCLS + n];
        slog[n] = acc * (1.0f / (float)HW);
    }
    __syncthreads();

    // softmax: threads < 256 replicate the old 256-thread reduce exactly
    int wid = tid >> 6, lane = tid & 63;
    float v[4];
    int cnt = 0;
    if (tid < 256) {
        float m = -1e30f;
        for (int i = tid; i < NCLS; i += 256) { float x = slog[i]; v[cnt++] = x; m = fmaxf(m, x); }
        #pragma unroll
        for (int off = 32; off > 0; off >>= 1) m = fmaxf(m, __shfl_xor(m, off, 64));
        if (lane == 0) red[wid] = m;
    }
    __syncthreads();
    float mm = fmaxf(fmaxf(red[0], red[1]), fmaxf(red[2], red[3]));
    __syncthreads();   // everyone done reading red before reuse

    if (tid < 256) {
        float s = 0.f;
        cnt = 0;
        for (int i = tid; i < NCLS; i += 256) { float e = expf(v[cnt++] - mm); slog[i] = e; s += e; }
        s = wave_reduce_sum(s);
        if (lane == 0) red[wid] = s;
    }
    __syncthreads();
    float inv = 1.0f / ((red[0] + red[1]) + (red[2] + red[3]));
    if (tid < 256) {
        for (int i = tid; i < NCLS; i += 256) slog[i] = slog[i] * inv - (1.0f / (float)NCLS);
    }
    __syncthreads();

    // gA: one c per thread, same float4 dot as before
    int c = tid;
    const float4* wr = reinterpret_cast<const float4*>(W + c * NCLS);
    float acc = 0.f;
    #pragma unroll 5
    for (int n = 0; n < NCLS / 4; ++n) {
        float4 wv = wr[n];
        acc += slog[4*n] * wv.x + slog[4*n+1] * wv.y + slog[4*n+2] * wv.z + slog[4*n+3] * wv.w;
    }
    gA[b * C_DIM + c] = acc * (ALPHA / (float)HW);
}

// ---------------- Kernel 3: states -> histogram ----------------------------
// Grid-stride like pool; per-row wave arithmetic identical to previous rounds.
__global__ void hist_kernel(const float* __restrict__ act,
                            const float* __restrict__ gA,
                            float* __restrict__ hist) {
    int wid  = threadIdx.x >> 6;
    int lane = threadIdx.x & 63;
    int wgid = blockIdx.x * 4 + wid;
    for (int row = wgid; row < NROWS; row += PH_BLOCKS * 4) {
        float g = gA[row];
        const float4* p = reinterpret_cast<const float4*>(act) + (size_t)row * HW4;
        float s = 0.f;
        #pragma unroll
        for (int i = 0; i < 3; ++i) {
            float4 v = p[lane + i * 64];
            s += 1.0f / (1.0f + expf(-g * v.x));
            s += 1.0f / (1.0f + expf(-g * v.y));
            s += 1.0f / (1.0f + expf(-g * v.z));
            s += 1.0f / (1.0f + expf(-g * v.w));
        }
        if (lane < 4) {
            float4 v = p[192 + lane];
            s += 1.0f / (1.0f + expf(-g * v.x));
            s += 1.0f / (1.0f + expf(-g * v.y));
            s += 1.0f / (1.0f + expf(-g * v.z));
            s += 1.0f / (1.0f + expf(-g * v.w));
        }
        s = wave_reduce_sum(s);
        if (lane == 0) {
            float st = s * (1.0f / (float)HW);
            int idx = (int)floorf(st * (float)MBINS);
            idx = idx < 0 ? 0 : (idx > MBINS - 1 ? MBINS - 1 : idx);
            int c = row & (C_DIM - 1);
            atomicAdd(hist + c * MBINS + idx, 1.0f);
        }
    }
}

extern "C" void kernel_launch(void* const* d_in, const int* in_sizes, int n_in,
                              void* d_out, int out_size, void* d_ws, size_t ws_size,
                              hipStream_t stream) {
    const float* act = (const float*)d_in[0];   // (B,C,H,W) fp32
    const float* W   = (const float*)d_in[1];   // (C,N) fp32
    float* hist      = (float*)d_out;           // (C, MBINS) fp32

    char* ws = (char*)d_ws;
    float* pooled = (float*)ws;                            // 65536 f
    float* gA     = (float*)(ws + (size_t)NROWS * 4);      // 65536 f

    pool_kernel      <<<PH_BLOCKS, 256, 0, stream>>>(act, pooled, hist);
    smax_gcalc_kernel<<<B_DIM, 512, 0, stream>>>(pooled, W, gA);
    hist_kernel      <<<PH_BLOCKS, 256, 0, stream>>>(act, gA, hist);
}

// Round 4
// 146.790 us; speedup vs baseline: 1.4402x; 1.4402x over previous
//
#include <hip/hip_runtime.h>
#include <math.h>

// Problem dims (fixed by the reference)
#define B_DIM   128
#define C_DIM   512
#define HW      784      // 28*28
#define HW4     196      // HW/4 float4s per (b,c) row
#define NCLS    1000
#define MBINS   50
#define NROWS   (B_DIM * C_DIM)   // 65536
#define ALPHA   100.0f
#define OUT_ELTS (C_DIM * MBINS)  // 25600 floats
#define PH_BLOCKS 2048            // pool/hist grid (grid-stride, 4 waves/block)

__device__ __forceinline__ float wave_reduce_sum(float v) {
    #pragma unroll
    for (int off = 32; off > 0; off >>= 1) v += __shfl_xor(v, off, 64);
    return v;
}

// ---------------- Kernel 1: spatial sum pool + d_out zeroing ---------------
// Grid-stride: 2048 blocks x 4 waves; per-row wave arithmetic identical to
// all previous passing rounds.
__global__ void pool_kernel(const float* __restrict__ act,
                            float* __restrict__ pooled,
                            float* __restrict__ hist_out) {
    if (blockIdx.x < OUT_ELTS / 256) {
        hist_out[blockIdx.x * 256 + threadIdx.x] = 0.0f;
    }
    int wid  = threadIdx.x >> 6;
    int lane = threadIdx.x & 63;
    int wgid = blockIdx.x * 4 + wid;
    for (int row = wgid; row < NROWS; row += PH_BLOCKS * 4) {
        const float4* p = reinterpret_cast<const float4*>(act) + (size_t)row * HW4;
        float s = 0.f;
        #pragma unroll
        for (int i = 0; i < 3; ++i) {
            float4 v = p[lane + i * 64];
            s += (v.x + v.y) + (v.z + v.w);
        }
        if (lane < 4) {
            float4 v = p[192 + lane];
            s += (v.x + v.y) + (v.z + v.w);
        }
        s = wave_reduce_sum(s);
        if (lane == 0) pooled[row] = s;
    }
}

// ---------------- Kernel 2: logits, quad-ILP --------------------------------
// grid (2, B) x 128 threads. Thread t of half h computes the 4 logits of quad
// q = h*125 + t via one float4 W load per c: 4 independent scalar FMA chains,
// each in ascending-c order -> bit-identical per-logit arithmetic to rounds
// 1-3. Wave reads 64 consecutive float4 = 1KB per c (fully coalesced, L2-hot).
__global__ void logits_kernel(const float* __restrict__ pooled,
                              const float* __restrict__ W,
                              float* __restrict__ logits) {
    __shared__ float sp[C_DIM];
    int b = blockIdx.y;
    int t = threadIdx.x;
    for (int c = t; c < C_DIM; c += 128) sp[c] = pooled[b * C_DIM + c];
    __syncthreads();
    if (t >= 125) return;
    int q = blockIdx.x * 125 + t;          // quad 0..249
    const float* wq = W + 4 * q;
    float ax = 0.f, ay = 0.f, az = 0.f, aw = 0.f;
    #pragma unroll 8
    for (int c = 0; c < C_DIM; ++c) {
        float4 wv = *reinterpret_cast<const float4*>(wq + (size_t)c * NCLS);
        float s = sp[c];
        ax += s * wv.x; ay += s * wv.y; az += s * wv.z; aw += s * wv.w;
    }
    float4 out;
    out.x = ax * (1.0f / (float)HW);
    out.y = ay * (1.0f / (float)HW);
    out.z = az * (1.0f / (float)HW);
    out.w = aw * (1.0f / (float)HW);
    *reinterpret_cast<float4*>(logits + (size_t)b * NCLS + 4 * q) = out;
}

// ---------------- Kernel 3: fused softmax + gA (round-2 version, verbatim) --
// grid (2, B) x 256. Each block: softmax(logits[b,:]) -> q in LDS (computed
// redundantly by both blocks of a b), then gA[b,c] for its 256 c's.
__global__ void smax_gcalc_kernel(const float* __restrict__ logits,
                                  const float* __restrict__ W,
                                  float* __restrict__ gA) {
    __shared__ float sq[NCLS];
    __shared__ float red[4];
    int b = blockIdx.y;
    const float* row = logits + b * NCLS;
    int tid = threadIdx.x, wid = tid >> 6, lane = tid & 63;

    float v[4];
    int cnt = 0;
    float m = -1e30f;
    for (int i = tid; i < NCLS; i += 256) { float x = row[i]; v[cnt++] = x; m = fmaxf(m, x); }
    #pragma unroll
    for (int off = 32; off > 0; off >>= 1) m = fmaxf(m, __shfl_xor(m, off, 64));
    if (lane == 0) red[wid] = m;
    __syncthreads();
    float mm = fmaxf(fmaxf(red[0], red[1]), fmaxf(red[2], red[3]));
    __syncthreads();   // everyone done reading red before reuse

    float s = 0.f;
    cnt = 0;
    for (int i = tid; i < NCLS; i += 256) { float e = expf(v[cnt++] - mm); sq[i] = e; s += e; }
    s = wave_reduce_sum(s);
    if (lane == 0) red[wid] = s;
    __syncthreads();   // also guarantees all sq[] writes visible
    float inv = 1.0f / ((red[0] + red[1]) + (red[2] + red[3]));

    for (int i = tid; i < NCLS; i += 256) sq[i] = sq[i] * inv - (1.0f / (float)NCLS);
    __syncthreads();

    int c = blockIdx.x * 256 + tid;
    const float4* wr = reinterpret_cast<const float4*>(W + (size_t)c * NCLS);
    float acc = 0.f;
    #pragma unroll 5
    for (int n = 0; n < NCLS / 4; ++n) {
        float4 wv = wr[n];
        acc += sq[4*n] * wv.x + sq[4*n+1] * wv.y + sq[4*n+2] * wv.z + sq[4*n+3] * wv.w;
    }
    gA[b * C_DIM + c] = acc * (ALPHA / (float)HW);
}

// ---------------- Kernel 4: states -> histogram ----------------------------
// Grid-stride; per-row wave arithmetic identical to previous rounds.
__global__ void hist_kernel(const float* __restrict__ act,
                            const float* __restrict__ gA,
                            float* __restrict__ hist) {
    int wid  = threadIdx.x >> 6;
    int lane = threadIdx.x & 63;
    int wgid = blockIdx.x * 4 + wid;
    for (int row = wgid; row < NROWS; row += PH_BLOCKS * 4) {
        float g = gA[row];
        const float4* p = reinterpret_cast<const float4*>(act) + (size_t)row * HW4;
        float s = 0.f;
        #pragma unroll
        for (int i = 0; i < 3; ++i) {
            float4 v = p[lane + i * 64];
            s += 1.0f / (1.0f + expf(-g * v.x));
            s += 1.0f / (1.0f + expf(-g * v.y));
            s += 1.0f / (1.0f + expf(-g * v.z));
            s += 1.0f / (1.0f + expf(-g * v.w));
        }
        if (lane < 4) {
            float4 v = p[192 + lane];
            s += 1.0f / (1.0f + expf(-g * v.x));
            s += 1.0f / (1.0f + expf(-g * v.y));
            s += 1.0f / (1.0f + expf(-g * v.z));
            s += 1.0f / (1.0f + expf(-g * v.w));
        }
        s = wave_reduce_sum(s);
        if (lane == 0) {
            float st = s * (1.0f / (float)HW);
            int idx = (int)floorf(st * (float)MBINS);
            idx = idx < 0 ? 0 : (idx > MBINS - 1 ? MBINS - 1 : idx);
            int c = row & (C_DIM - 1);
            atomicAdd(hist + c * MBINS + idx, 1.0f);
        }
    }
}

extern "C" void kernel_launch(void* const* d_in, const int* in_sizes, int n_in,
                              void* d_out, int out_size, void* d_ws, size_t ws_size,
                              hipStream_t stream) {
    const float* act = (const float*)d_in[0];   // (B,C,H,W) fp32
    const float* W   = (const float*)d_in[1];   // (C,N) fp32
    float* hist      = (float*)d_out;           // (C, MBINS) fp32

    char* ws = (char*)d_ws;
    float* pooled = (float*)ws;                                   // 65536 f
    float* logits = (float*)(ws + (size_t)NROWS * 4);             // 128000 f
    float* gA     = (float*)(ws + (size_t)NROWS * 4
                                + (size_t)B_DIM * NCLS * 4);      // 65536 f

    pool_kernel      <<<PH_BLOCKS, 256, 0, stream>>>(act, pooled, hist);
    logits_kernel    <<<dim3(2, B_DIM), 128, 0, stream>>>(pooled, W, logits);
    smax_gcalc_kernel<<<dim3(2, B_DIM), 256, 0, stream>>>(logits, W, gA);
    hist_kernel      <<<PH_BLOCKS, 256, 0, stream>>>(act, gA, hist);
}

// Round 5
// 127.829 us; speedup vs baseline: 1.6538x; 1.1483x over previous
//
#include <hip/hip_runtime.h>
#include <math.h>

// Problem dims (fixed by the reference)
#define B_DIM   128
#define C_DIM   512
#define HW      784      // 28*28
#define HW4     196      // HW/4 float4s per (b,c) row
#define NCLS    1000
#define MBINS   50
#define NROWS   (B_DIM * C_DIM)   // 65536
#define ALPHA   100.0f
#define OUT_ELTS (C_DIM * MBINS)  // 25600 floats
#define PH_BLOCKS 2048            // pool/hist grid (grid-stride, 4 waves/block)

__device__ __forceinline__ float wave_reduce_sum(float v) {
    #pragma unroll
    for (int off = 32; off > 0; off >>= 1) v += __shfl_xor(v, off, 64);
    return v;
}

// ---------------- Kernel 1: spatial sum pool + d_out zeroing ---------------
__global__ void pool_kernel(const float* __restrict__ act,
                            float* __restrict__ pooled,
                            float* __restrict__ hist_out) {
    if (blockIdx.x < OUT_ELTS / 256) {
        hist_out[blockIdx.x * 256 + threadIdx.x] = 0.0f;
    }
    int wid  = threadIdx.x >> 6;
    int lane = threadIdx.x & 63;
    int wgid = blockIdx.x * 4 + wid;
    for (int row = wgid; row < NROWS; row += PH_BLOCKS * 4) {
        const float4* p = reinterpret_cast<const float4*>(act) + (size_t)row * HW4;
        float s = 0.f;
        #pragma unroll
        for (int i = 0; i < 3; ++i) {
            float4 v = p[lane + i * 64];
            s += (v.x + v.y) + (v.z + v.w);
        }
        if (lane < 4) {
            float4 v = p[192 + lane];
            s += (v.x + v.y) + (v.z + v.w);
        }
        s = wave_reduce_sum(s);
        if (lane == 0) pooled[row] = s;
    }
}

// ---------------- Kernel 1b: W transpose (layout only, no numerics) ---------
// WT[n][c] = W[c][n]. 32x32 LDS tiles, +1 pad. grid (32, 16) x 256.
__global__ void transpose_kernel(const float* __restrict__ W,
                                 float* __restrict__ WT) {
    __shared__ float tile[32][33];
    int n0 = blockIdx.x * 32;
    int c0 = blockIdx.y * 32;
    int tx = threadIdx.x & 31;        // fast dim
    int ty = threadIdx.x >> 5;        // 0..7
    #pragma unroll
    for (int p = 0; p < 4; ++p) {
        int cl = ty + p * 8;          // c_local 0..31
        int n  = n0 + tx;
        if (n < NCLS) tile[cl][tx] = W[(size_t)(c0 + cl) * NCLS + n];
    }
    __syncthreads();
    #pragma unroll
    for (int p = 0; p < 4; ++p) {
        int nl = ty + p * 8;          // n_local 0..31
        int n  = n0 + nl;
        if (n < NCLS) WT[(size_t)n * C_DIM + c0 + tx] = tile[tx][nl];
    }
}

// ---------------- Kernel 2: logits ------------------------------------------
// grid (4, B) x 256: one (b,n) per thread = 2048 waves (8/CU). Scalar
// ascending-c chain, bit-identical to rounds 1-2. W loads coalesced
// (n across lanes, 256B/wave-load), unroll 16 for in-flight depth.
__global__ void logits_kernel(const float* __restrict__ pooled,
                              const float* __restrict__ W,
                              float* __restrict__ logits) {
    __shared__ float sp[C_DIM];
    int b = blockIdx.y;
    int tid = threadIdx.x;
    for (int c = tid; c < C_DIM; c += 256) sp[c] = pooled[b * C_DIM + c];
    __syncthreads();
    int n = blockIdx.x * 256 + tid;
    if (n >= NCLS) return;
    float acc = 0.f;
    #pragma unroll 16
    for (int c = 0; c < C_DIM; ++c) acc += sp[c] * W[(size_t)c * NCLS + n];
    logits[(size_t)b * NCLS + n] = acc * (1.0f / (float)HW);
}

// ---------------- Kernel 3: fused softmax + gA (reads WT, coalesced) --------
// grid (2, B) x 256. Softmax part is round-2 code verbatim (bit-identical).
// gA dot keeps the exact float4-group expression tree of all passing rounds:
//   acc += sq[4i]*w0 + sq[4i+1]*w1 + sq[4i+2]*w2 + sq[4i+3]*w3
// but loads w0..w3 from WT with c across lanes -> 4 coalesced 256B wave-loads.
__global__ void smax_gcalc_kernel(const float* __restrict__ logits,
                                  const float* __restrict__ WT,
                                  float* __restrict__ gA) {
    __shared__ float sq[NCLS];
    __shared__ float red[4];
    int b = blockIdx.y;
    const float* row = logits + (size_t)b * NCLS;
    int tid = threadIdx.x, wid = tid >> 6, lane = tid & 63;

    float v[4];
    int cnt = 0;
    float m = -1e30f;
    for (int i = tid; i < NCLS; i += 256) { float x = row[i]; v[cnt++] = x; m = fmaxf(m, x); }
    #pragma unroll
    for (int off = 32; off > 0; off >>= 1) m = fmaxf(m, __shfl_xor(m, off, 64));
    if (lane == 0) red[wid] = m;
    __syncthreads();
    float mm = fmaxf(fmaxf(red[0], red[1]), fmaxf(red[2], red[3]));
    __syncthreads();   // everyone done reading red before reuse

    float s = 0.f;
    cnt = 0;
    for (int i = tid; i < NCLS; i += 256) { float e = expf(v[cnt++] - mm); sq[i] = e; s += e; }
    s = wave_reduce_sum(s);
    if (lane == 0) red[wid] = s;
    __syncthreads();   // also guarantees all sq[] writes visible
    float inv = 1.0f / ((red[0] + red[1]) + (red[2] + red[3]));

    for (int i = tid; i < NCLS; i += 256) sq[i] = sq[i] * inv - (1.0f / (float)NCLS);
    __syncthreads();

    int c = blockIdx.x * 256 + tid;
    const float* wt = WT + c;
    float acc = 0.f;
    #pragma unroll 10
    for (int i = 0; i < NCLS / 4; ++i) {
        float w0 = wt[(size_t)(4*i+0) * C_DIM];
        float w1 = wt[(size_t)(4*i+1) * C_DIM];
        float w2 = wt[(size_t)(4*i+2) * C_DIM];
        float w3 = wt[(size_t)(4*i+3) * C_DIM];
        acc += sq[4*i] * w0 + sq[4*i+1] * w1 + sq[4*i+2] * w2 + sq[4*i+3] * w3;
    }
    gA[(size_t)b * C_DIM + c] = acc * (ALPHA / (float)HW);
}

// ---------------- Kernel 4: states -> histogram ----------------------------
__global__ void hist_kernel(const float* __restrict__ act,
                            const float* __restrict__ gA,
                            float* __restrict__ hist) {
    int wid  = threadIdx.x >> 6;
    int lane = threadIdx.x & 63;
    int wgid = blockIdx.x * 4 + wid;
    for (int row = wgid; row < NROWS; row += PH_BLOCKS * 4) {
        float g = gA[row];
        const float4* p = reinterpret_cast<const float4*>(act) + (size_t)row * HW4;
        float s = 0.f;
        #pragma unroll
        for (int i = 0; i < 3; ++i) {
            float4 v = p[lane + i * 64];
            s += 1.0f / (1.0f + expf(-g * v.x));
            s += 1.0f / (1.0f + expf(-g * v.y));
            s += 1.0f / (1.0f + expf(-g * v.z));
            s += 1.0f / (1.0f + expf(-g * v.w));
        }
        if (lane < 4) {
            float4 v = p[192 + lane];
            s += 1.0f / (1.0f + expf(-g * v.x));
            s += 1.0f / (1.0f + expf(-g * v.y));
            s += 1.0f / (1.0f + expf(-g * v.z));
            s += 1.0f / (1.0f + expf(-g * v.w));
        }
        s = wave_reduce_sum(s);
        if (lane == 0) {
            float st = s * (1.0f / (float)HW);
            int idx = (int)floorf(st * (float)MBINS);
            idx = idx < 0 ? 0 : (idx > MBINS - 1 ? MBINS - 1 : idx);
            int c = row & (C_DIM - 1);
            atomicAdd(hist + c * MBINS + idx, 1.0f);
        }
    }
}

extern "C" void kernel_launch(void* const* d_in, const int* in_sizes, int n_in,
                              void* d_out, int out_size, void* d_ws, size_t ws_size,
                              hipStream_t stream) {
    const float* act = (const float*)d_in[0];   // (B,C,H,W) fp32
    const float* W   = (const float*)d_in[1];   // (C,N) fp32
    float* hist      = (float*)d_out;           // (C, MBINS) fp32

    char* ws = (char*)d_ws;
    float* pooled = (float*)(ws);                       // 256 KB @ 0
    float* gA     = (float*)(ws + (1u << 18));          // 256 KB @ 256K
    float* logits = (float*)(ws + (1u << 19));          // 500 KB @ 512K
    float* WT     = (float*)(ws + (1u << 20));          // 2 MB  @ 1M

    pool_kernel      <<<PH_BLOCKS, 256, 0, stream>>>(act, pooled, hist);
    transpose_kernel <<<dim3(32, 16), 256, 0, stream>>>(W, WT);
    logits_kernel    <<<dim3(4, B_DIM), 256, 0, stream>>>(pooled, W, logits);
    smax_gcalc_kernel<<<dim3(2, B_DIM), 256, 0, stream>>>(logits, WT, gA);
    hist_kernel      <<<PH_BLOCKS, 256, 0, stream>>>(act, gA, hist);
}